// Round 5
// baseline (550.824 us; speedup 1.0000x reference)
//
#include <hip/hip_runtime.h>
#include <math.h>

#define N_NODES 50000
#define N_EDGES 800000
#define D 64
#define NB_SCAN ((N_NODES + 255) / 256)   // 196 blocks of 256

typedef float f32x4 __attribute__((ext_vector_type(4)));   // native vector for nontemporal builtins

// ---------------------------------------------------------------------------
// Phase 1: histogram of src -> cnt[n]  (int atomics, 800K ops)
// ---------------------------------------------------------------------------
__global__ __launch_bounds__(256) void hist_kernel(
    const int* __restrict__ edge_index, int* __restrict__ cnt)
{
    int e = blockIdx.x * blockDim.x + threadIdx.x;
    if (e >= N_EDGES) return;
    atomicAdd(&cnt[edge_index[e]], 1);
}

// ---------------------------------------------------------------------------
// Phase 2: exclusive scan of cnt -> offs  (3 tiny kernels)
// ---------------------------------------------------------------------------
__global__ __launch_bounds__(256) void scanA_kernel(
    const int* __restrict__ cnt, int* __restrict__ offs, int* __restrict__ bsum)
{
    __shared__ int tmp[256];
    int tid = threadIdx.x;
    int i = blockIdx.x * 256 + tid;
    int v = (i < N_NODES) ? cnt[i] : 0;
    tmp[tid] = v;
    __syncthreads();
    for (int s = 1; s < 256; s <<= 1) {
        int add = (tid >= s) ? tmp[tid - s] : 0;
        __syncthreads();
        tmp[tid] += add;
        __syncthreads();
    }
    if (i < N_NODES) offs[i] = tmp[tid] - v;          // exclusive
    if (tid == 255) bsum[blockIdx.x] = tmp[255];      // block total
}

__global__ __launch_bounds__(256) void scanB_kernel(int* __restrict__ bsum)
{
    __shared__ int tmp[256];
    int tid = threadIdx.x;
    int v = (tid < NB_SCAN) ? bsum[tid] : 0;
    tmp[tid] = v;
    __syncthreads();
    for (int s = 1; s < 256; s <<= 1) {
        int add = (tid >= s) ? tmp[tid - s] : 0;
        __syncthreads();
        tmp[tid] += add;
        __syncthreads();
    }
    bsum[tid] = tmp[tid] - v;                          // exclusive block offsets
}

__global__ __launch_bounds__(256) void scanC_kernel(
    int* __restrict__ offs, const int* __restrict__ bsum, int* __restrict__ cursor)
{
    int i = blockIdx.x * 256 + threadIdx.x;
    if (i >= N_NODES) return;
    int o = offs[i] + bsum[blockIdx.x];
    offs[i] = o;
    cursor[i] = o;
}

// ---------------------------------------------------------------------------
// Phase 3: bucket edge ids by src (counting-sort fill)
// ---------------------------------------------------------------------------
__global__ __launch_bounds__(256) void fill_kernel(
    const int* __restrict__ edge_index, int* __restrict__ cursor,
    int* __restrict__ bucket)
{
    int e = blockIdx.x * blockDim.x + threadIdx.x;
    if (e >= N_EDGES) return;
    int src = edge_index[e];
    int pos = atomicAdd(&cursor[src], 1);
    bucket[pos] = e;
}

// ---------------------------------------------------------------------------
// Phase 4 (fused): per-node gather-mean + linear + sigmoid. (unchanged)
// ---------------------------------------------------------------------------
__global__ __launch_bounds__(256) void node_fused_kernel(
    const float* __restrict__ node_attr,
    const float* __restrict__ edge_attr,
    const int* __restrict__ cnt,
    const int* __restrict__ offs,
    const int* __restrict__ bucket,
    const float* __restrict__ W,
    const float* __restrict__ bias,
    float* __restrict__ node_emb)
{
    __shared__ float Wt[D * (D + 1)];     // Wt[i*65+o] = W[o][i]; 2-way banks everywhere
    __shared__ f32x4 msbuf[4][16];        // per-wave ms row (64 floats as 16 quads)
    int tid = threadIdx.x;
    for (int k = tid; k < D * D; k += 256) {
        int o = k >> 6, i = k & 63;
        Wt[i * (D + 1) + o] = W[k];
    }
    __syncthreads();

    int wv   = tid >> 6;
    int n    = blockIdx.x * 4 + wv;
    int lane = tid & 63;
    if (n >= N_NODES) return;

    int c   = cnt[n];
    int beg = offs[n];
    const int* __restrict__ bk = bucket + beg;

    int sub = lane >> 4;          // 0..3
    int q   = lane & 15;          // feature quad

    f32x4 s0 = {0.f,0.f,0.f,0.f}, s1 = s0, s2 = s0, s3 = s0;
    int k = 0;
    for (; k + 16 <= c; k += 16) {
        int ea = bk[k +  0 + sub];
        int eb = bk[k +  4 + sub];
        int ec = bk[k +  8 + sub];
        int ed = bk[k + 12 + sub];
        s0 += ((const f32x4*)(edge_attr + (size_t)ea * D))[q];
        s1 += ((const f32x4*)(edge_attr + (size_t)eb * D))[q];
        s2 += ((const f32x4*)(edge_attr + (size_t)ec * D))[q];
        s3 += ((const f32x4*)(edge_attr + (size_t)ed * D))[q];
    }
    for (; k + 4 <= c; k += 4) {
        int ea = bk[k + sub];
        s0 += ((const f32x4*)(edge_attr + (size_t)ea * D))[q];
    }
    int rem = c - k;              // 0..3 leftover edges
    if (sub < rem) {
        int ea = bk[k + sub];
        s1 += ((const f32x4*)(edge_attr + (size_t)ea * D))[q];
    }
    f32x4 s = (s0 + s1) + (s2 + s3);

    // reduce across the 4 sub-groups: lanes l, l^16, l^32, l^48
    s.x += __shfl_xor(s.x, 16, 64); s.y += __shfl_xor(s.y, 16, 64);
    s.z += __shfl_xor(s.z, 16, 64); s.w += __shfl_xor(s.w, 16, 64);
    s.x += __shfl_xor(s.x, 32, 64); s.y += __shfl_xor(s.y, 32, 64);
    s.z += __shfl_xor(s.z, 32, 64); s.w += __shfl_xor(s.w, 32, 64);

    float scale = 0.5f / (float)((c > 0) ? c : 1);
    f32x4 na = ((const f32x4*)(node_attr + (size_t)n * D))[q];
    f32x4 ms = na + s * scale;    // every lane holds features 4q..4q+3 (replicated over sub)

    // publish ms row to per-wave LDS buffer (sub==0 lanes: 16 lanes x 16 B)
    if (sub == 0) msbuf[wv][q] = ms;
    asm volatile("s_waitcnt lgkmcnt(0)" ::: "memory");
    __builtin_amdgcn_sched_barrier(0);

    float acc = bias[lane];
    const f32x4* __restrict__ mrow = msbuf[wv];
    #pragma unroll
    for (int ii = 0; ii < 16; ++ii) {
        f32x4 mm = mrow[ii];                       // wave-uniform broadcast read
        acc = fmaf(mm.x, Wt[(4 * ii + 0) * (D + 1) + lane], acc);
        acc = fmaf(mm.y, Wt[(4 * ii + 1) * (D + 1) + lane], acc);
        acc = fmaf(mm.z, Wt[(4 * ii + 2) * (D + 1) + lane], acc);
        acc = fmaf(mm.w, Wt[(4 * ii + 3) * (D + 1) + lane], acc);
    }
    node_emb[(size_t)n * D + lane] = 1.0f / (1.0f + __expf(-acc));
}

// ---------------------------------------------------------------------------
// Phase 5: out[e] = 0.5*(node_emb[src[e]] + node_emb[dst[e]])
// CHANGED THIS ROUND: iterate edges in bucket (src-sorted) order. Consecutive
// thread-groups share the same src row (~16 edges/node), so the src half of
// the 410 MB logical gather becomes L1/L2 hits instead of random L3 traffic.
// dst stays random; out writes become scattered 256-B NT chunks (4 full
// 64-B lines each -> near-full HBM write efficiency).
// ---------------------------------------------------------------------------
__global__ __launch_bounds__(256) void edge_kernel(
    const int* __restrict__ edge_index,
    const int* __restrict__ bucket,       // src-sorted edge ids (permutation)
    const f32x4* __restrict__ node_emb,   // [N_NODES*16] vec4
    f32x4* __restrict__ out)              // [N_EDGES*16] vec4
{
    int t = blockIdx.x * blockDim.x + threadIdx.x;   // < E*8 = 6.4M
    if (t >= N_EDGES * 8) return;
    int b = t >> 3;                // bucket position (src-sorted)
    int q = t & 7;                 // 32-B chunk within the row
    int e = bucket[b];             // actual edge id (wave-uniform per 8 lanes)
    int src = edge_index[e];
    int dst = edge_index[N_EDGES + e];
    f32x4 a0 = node_emb[src * 16 + 2 * q];
    f32x4 a1 = node_emb[src * 16 + 2 * q + 1];
    f32x4 c0 = node_emb[dst * 16 + 2 * q];
    f32x4 c1 = node_emb[dst * 16 + 2 * q + 1];
    size_t o = (size_t)e * 16 + 2 * q;
    __builtin_nontemporal_store((a0 + c0) * 0.5f, out + o);
    __builtin_nontemporal_store((a1 + c1) * 0.5f, out + o + 1);
}

extern "C" void kernel_launch(void* const* d_in, const int* in_sizes, int n_in,
                              void* d_out, int out_size, void* d_ws, size_t ws_size,
                              hipStream_t stream) {
    const float* edge_attr  = (const float*)d_in[0];
    const int*   edge_index = (const int*)d_in[1];
    const float* node_attr  = (const float*)d_in[2];
    const float* W          = (const float*)d_in[3];
    const float* bias       = (const float*)d_in[4];
    float* out = (float*)d_out;

    // Workspace layout:
    //   cnt    : int[N_NODES]      @ 0
    //   offs   : int[N_NODES]      @ 200000 B
    //   bsum   : int[256]          @ 400000 B
    //   cursor : int[N_NODES]      @ 401024 B
    //   bucket : int[N_EDGES]      @ 601024 B
    //   node_emb: float[N_NODES*D] @ 3801024 B (16B-aligned)
    char* ws = (char*)d_ws;
    int*   cnt      = (int*)(ws);
    int*   offs     = (int*)(ws + 200000);
    int*   bsum     = (int*)(ws + 400000);
    int*   cursor   = (int*)(ws + 401024);
    int*   bucket   = (int*)(ws + 601024);
    float* node_emb = (float*)(ws + 3801024);

    hipMemsetAsync(cnt, 0, N_NODES * sizeof(int), stream);

    hist_kernel<<<(N_EDGES + 255) / 256, 256, 0, stream>>>(edge_index, cnt);
    scanA_kernel<<<NB_SCAN, 256, 0, stream>>>(cnt, offs, bsum);
    scanB_kernel<<<1, 256, 0, stream>>>(bsum);
    scanC_kernel<<<NB_SCAN, 256, 0, stream>>>(offs, bsum, cursor);
    fill_kernel<<<(N_EDGES + 255) / 256, 256, 0, stream>>>(edge_index, cursor, bucket);
    node_fused_kernel<<<(N_NODES + 3) / 4, 256, 0, stream>>>(
        node_attr, edge_attr, cnt, offs, bucket, W, bias, node_emb);
    edge_kernel<<<(N_EDGES * 8 + 255) / 256, 256, 0, stream>>>(
        edge_index, bucket, (const f32x4*)node_emb, (f32x4*)out);
}

// Round 6
// 509.533 us; speedup vs baseline: 1.0810x; 1.0810x over previous
//
#include <hip/hip_runtime.h>
#include <hip/hip_fp16.h>
#include <math.h>

#define N_NODES 50000
#define N_EDGES 800000
#define D 64
#define NB_SCAN ((N_NODES + 255) / 256)   // 196 blocks of 256

typedef float f32x4 __attribute__((ext_vector_type(4)));   // native vector for nontemporal builtins

// ---------------------------------------------------------------------------
// Phase 1: histogram of src -> cnt[n]  (int atomics, 800K ops)
// ---------------------------------------------------------------------------
__global__ __launch_bounds__(256) void hist_kernel(
    const int* __restrict__ edge_index, int* __restrict__ cnt)
{
    int e = blockIdx.x * blockDim.x + threadIdx.x;
    if (e >= N_EDGES) return;
    atomicAdd(&cnt[edge_index[e]], 1);
}

// ---------------------------------------------------------------------------
// Phase 2: exclusive scan of cnt -> offs  (3 tiny kernels)
// ---------------------------------------------------------------------------
__global__ __launch_bounds__(256) void scanA_kernel(
    const int* __restrict__ cnt, int* __restrict__ offs, int* __restrict__ bsum)
{
    __shared__ int tmp[256];
    int tid = threadIdx.x;
    int i = blockIdx.x * 256 + tid;
    int v = (i < N_NODES) ? cnt[i] : 0;
    tmp[tid] = v;
    __syncthreads();
    for (int s = 1; s < 256; s <<= 1) {
        int add = (tid >= s) ? tmp[tid - s] : 0;
        __syncthreads();
        tmp[tid] += add;
        __syncthreads();
    }
    if (i < N_NODES) offs[i] = tmp[tid] - v;          // exclusive
    if (tid == 255) bsum[blockIdx.x] = tmp[255];      // block total
}

__global__ __launch_bounds__(256) void scanB_kernel(int* __restrict__ bsum)
{
    __shared__ int tmp[256];
    int tid = threadIdx.x;
    int v = (tid < NB_SCAN) ? bsum[tid] : 0;
    tmp[tid] = v;
    __syncthreads();
    for (int s = 1; s < 256; s <<= 1) {
        int add = (tid >= s) ? tmp[tid - s] : 0;
        __syncthreads();
        tmp[tid] += add;
        __syncthreads();
    }
    bsum[tid] = tmp[tid] - v;                          // exclusive block offsets
}

__global__ __launch_bounds__(256) void scanC_kernel(
    int* __restrict__ offs, const int* __restrict__ bsum, int* __restrict__ cursor)
{
    int i = blockIdx.x * 256 + threadIdx.x;
    if (i >= N_NODES) return;
    int o = offs[i] + bsum[blockIdx.x];
    offs[i] = o;
    cursor[i] = o;
}

// ---------------------------------------------------------------------------
// Phase 3: bucket edge ids by src (counting-sort fill)
// ---------------------------------------------------------------------------
__global__ __launch_bounds__(256) void fill_kernel(
    const int* __restrict__ edge_index, int* __restrict__ cursor,
    int* __restrict__ bucket)
{
    int e = blockIdx.x * blockDim.x + threadIdx.x;
    if (e >= N_EDGES) return;
    int src = edge_index[e];
    int pos = atomicAdd(&cursor[src], 1);
    bucket[pos] = e;
}

// ---------------------------------------------------------------------------
// Phase 4 (fused): per-node gather-mean + linear + sigmoid.
// Unchanged from round 4 except: node_emb is now stored as FP16 (half the
// intermediate table -> half the random-read bytes in edge_kernel, and the
// 6.4 MB table nearly fits a single XCD's 4 MB L2).
// ---------------------------------------------------------------------------
__global__ __launch_bounds__(256) void node_fused_kernel(
    const float* __restrict__ node_attr,
    const float* __restrict__ edge_attr,
    const int* __restrict__ cnt,
    const int* __restrict__ offs,
    const int* __restrict__ bucket,
    const float* __restrict__ W,
    const float* __restrict__ bias,
    __half* __restrict__ node_emb)
{
    __shared__ float Wt[D * (D + 1)];     // Wt[i*65+o] = W[o][i]; 2-way banks everywhere
    __shared__ f32x4 msbuf[4][16];        // per-wave ms row (64 floats as 16 quads)
    int tid = threadIdx.x;
    for (int k = tid; k < D * D; k += 256) {
        int o = k >> 6, i = k & 63;
        Wt[i * (D + 1) + o] = W[k];
    }
    __syncthreads();

    int wv   = tid >> 6;
    int n    = blockIdx.x * 4 + wv;
    int lane = tid & 63;
    if (n >= N_NODES) return;

    int c   = cnt[n];
    int beg = offs[n];
    const int* __restrict__ bk = bucket + beg;

    int sub = lane >> 4;          // 0..3
    int q   = lane & 15;          // feature quad

    f32x4 s0 = {0.f,0.f,0.f,0.f}, s1 = s0, s2 = s0, s3 = s0;
    int k = 0;
    for (; k + 16 <= c; k += 16) {
        int ea = bk[k +  0 + sub];
        int eb = bk[k +  4 + sub];
        int ec = bk[k +  8 + sub];
        int ed = bk[k + 12 + sub];
        s0 += ((const f32x4*)(edge_attr + (size_t)ea * D))[q];
        s1 += ((const f32x4*)(edge_attr + (size_t)eb * D))[q];
        s2 += ((const f32x4*)(edge_attr + (size_t)ec * D))[q];
        s3 += ((const f32x4*)(edge_attr + (size_t)ed * D))[q];
    }
    for (; k + 4 <= c; k += 4) {
        int ea = bk[k + sub];
        s0 += ((const f32x4*)(edge_attr + (size_t)ea * D))[q];
    }
    int rem = c - k;              // 0..3 leftover edges
    if (sub < rem) {
        int ea = bk[k + sub];
        s1 += ((const f32x4*)(edge_attr + (size_t)ea * D))[q];
    }
    f32x4 s = (s0 + s1) + (s2 + s3);

    // reduce across the 4 sub-groups: lanes l, l^16, l^32, l^48
    s.x += __shfl_xor(s.x, 16, 64); s.y += __shfl_xor(s.y, 16, 64);
    s.z += __shfl_xor(s.z, 16, 64); s.w += __shfl_xor(s.w, 16, 64);
    s.x += __shfl_xor(s.x, 32, 64); s.y += __shfl_xor(s.y, 32, 64);
    s.z += __shfl_xor(s.z, 32, 64); s.w += __shfl_xor(s.w, 32, 64);

    float scale = 0.5f / (float)((c > 0) ? c : 1);
    f32x4 na = ((const f32x4*)(node_attr + (size_t)n * D))[q];
    f32x4 ms = na + s * scale;    // every lane holds features 4q..4q+3 (replicated over sub)

    // publish ms row to per-wave LDS buffer (sub==0 lanes: 16 lanes x 16 B)
    if (sub == 0) msbuf[wv][q] = ms;
    asm volatile("s_waitcnt lgkmcnt(0)" ::: "memory");
    __builtin_amdgcn_sched_barrier(0);

    float acc = bias[lane];
    const f32x4* __restrict__ mrow = msbuf[wv];
    #pragma unroll
    for (int ii = 0; ii < 16; ++ii) {
        f32x4 mm = mrow[ii];                       // wave-uniform broadcast read
        acc = fmaf(mm.x, Wt[(4 * ii + 0) * (D + 1) + lane], acc);
        acc = fmaf(mm.y, Wt[(4 * ii + 1) * (D + 1) + lane], acc);
        acc = fmaf(mm.z, Wt[(4 * ii + 2) * (D + 1) + lane], acc);
        acc = fmaf(mm.w, Wt[(4 * ii + 3) * (D + 1) + lane], acc);
    }
    float sg = 1.0f / (1.0f + __expf(-acc));
    node_emb[(size_t)n * D + lane] = __float2half(sg);   // 2 B/lane, 128 B/wave coalesced
}

// ---------------------------------------------------------------------------
// Phase 5: out[e] = 0.5*(node_emb[src[e]] + node_emb[dst[e]])
// REVERTED to round-4 sequential-in-e form (round-5 src-sorted order
// regressed: scattered writes cost more than the read-locality gained).
// node_emb is fp16: one 16-B load per thread covers 8 features; 8 threads
// cover a 128-B row. Reads halve to 205 MB logical; writes stay sequential
// 205 MB NT.
// ---------------------------------------------------------------------------
__global__ __launch_bounds__(256) void edge_kernel(
    const int* __restrict__ edge_index,
    const f32x4* __restrict__ node_emb_v,  // fp16 rows viewed as 16-B chunks: [N_NODES*8]
    f32x4* __restrict__ out)               // [N_EDGES*16] vec4
{
    int t = blockIdx.x * blockDim.x + threadIdx.x;   // < E*8 = 6.4M
    if (t >= N_EDGES * 8) return;
    int e = t >> 3;
    int q = t & 7;                 // 16-B chunk of the fp16 row = 8 features
    int src = edge_index[e];
    int dst = edge_index[N_EDGES + e];

    union { f32x4 v; __half2 h[4]; } ua, ub;
    ua.v = node_emb_v[src * 8 + q];
    ub.v = node_emb_v[dst * 8 + q];

    f32x4 r0, r1;
    {
        float2 a0 = __half22float2(ua.h[0]), b0 = __half22float2(ub.h[0]);
        float2 a1 = __half22float2(ua.h[1]), b1 = __half22float2(ub.h[1]);
        r0.x = (a0.x + b0.x) * 0.5f; r0.y = (a0.y + b0.y) * 0.5f;
        r0.z = (a1.x + b1.x) * 0.5f; r0.w = (a1.y + b1.y) * 0.5f;
        float2 a2 = __half22float2(ua.h[2]), b2 = __half22float2(ub.h[2]);
        float2 a3 = __half22float2(ua.h[3]), b3 = __half22float2(ub.h[3]);
        r1.x = (a2.x + b2.x) * 0.5f; r1.y = (a2.y + b2.y) * 0.5f;
        r1.z = (a3.x + b3.x) * 0.5f; r1.w = (a3.y + b3.y) * 0.5f;
    }
    size_t o = (size_t)e * 16 + 2 * q;     // 8 floats = 2 f32x4, sequential in e
    __builtin_nontemporal_store(r0, out + o);
    __builtin_nontemporal_store(r1, out + o + 1);
}

extern "C" void kernel_launch(void* const* d_in, const int* in_sizes, int n_in,
                              void* d_out, int out_size, void* d_ws, size_t ws_size,
                              hipStream_t stream) {
    const float* edge_attr  = (const float*)d_in[0];
    const int*   edge_index = (const int*)d_in[1];
    const float* node_attr  = (const float*)d_in[2];
    const float* W          = (const float*)d_in[3];
    const float* bias       = (const float*)d_in[4];
    float* out = (float*)d_out;

    // Workspace layout:
    //   cnt    : int[N_NODES]        @ 0
    //   offs   : int[N_NODES]        @ 200000 B
    //   bsum   : int[256]            @ 400000 B
    //   cursor : int[N_NODES]        @ 401024 B
    //   bucket : int[N_EDGES]        @ 601024 B
    //   node_emb: half[N_NODES*D]    @ 3801024 B (16B-aligned, 6.4 MB)
    char* ws = (char*)d_ws;
    int*    cnt      = (int*)(ws);
    int*    offs     = (int*)(ws + 200000);
    int*    bsum     = (int*)(ws + 400000);
    int*    cursor   = (int*)(ws + 401024);
    int*    bucket   = (int*)(ws + 601024);
    __half* node_emb = (__half*)(ws + 3801024);

    hipMemsetAsync(cnt, 0, N_NODES * sizeof(int), stream);

    hist_kernel<<<(N_EDGES + 255) / 256, 256, 0, stream>>>(edge_index, cnt);
    scanA_kernel<<<NB_SCAN, 256, 0, stream>>>(cnt, offs, bsum);
    scanB_kernel<<<1, 256, 0, stream>>>(bsum);
    scanC_kernel<<<NB_SCAN, 256, 0, stream>>>(offs, bsum, cursor);
    fill_kernel<<<(N_EDGES + 255) / 256, 256, 0, stream>>>(edge_index, cursor, bucket);
    node_fused_kernel<<<(N_NODES + 3) / 4, 256, 0, stream>>>(
        node_attr, edge_attr, cnt, offs, bucket, W, bias, node_emb);
    edge_kernel<<<(N_EDGES * 8 + 255) / 256, 256, 0, stream>>>(
        edge_index, (const f32x4*)node_emb, (f32x4*)out);
}